// Round 2
// baseline (1904.474 us; speedup 1.0000x reference)
//
#include <hip/hip_runtime.h>
#include <hip/hip_bf16.h>
#include <math.h>

// Problem constants (from reference)
#define B_   4
#define S_   4000
#define DIN  1024
#define DA   512
#define L_   8921

typedef __attribute__((ext_vector_type(8))) short          short8;  // 8 bf16 = 4 VGPRs (MFMA A/B frag)
typedef __attribute__((ext_vector_type(4))) float          f4;      // 4 f32 (MFMA C/D frag)
typedef __attribute__((ext_vector_type(4))) unsigned int   u4;      // 16B vector for LDS/global moves
typedef __attribute__((ext_vector_type(4))) unsigned short us4;     // 8B vector (4 bf16)

// f32 -> bf16 round-to-nearest-even (finite inputs only; fine here)
static __device__ __forceinline__ unsigned short f2b(float f) {
    unsigned int u = __float_as_uint(f);
    u += 0x7fffu + ((u >> 16) & 1u);
    return (unsigned short)(u >> 16);
}
static __device__ __forceinline__ unsigned int pack2(float lo, float hi) {
    return (unsigned int)f2b(lo) | ((unsigned int)f2b(hi) << 16);
}
static __device__ __forceinline__ float b2f(unsigned short u) {
    return __uint_as_float(((unsigned int)u) << 16);
}

// Direct global->LDS copy, 16B per lane. LDS dest must be lane-linear
// (wave-uniform base + lane*16) — our K-major chunk layout guarantees it.
static __device__ __forceinline__ void gload16(const unsigned short* g, unsigned short* l) {
    __builtin_amdgcn_global_load_lds(
        (const __attribute__((address_space(1))) unsigned int*)g,
        (__attribute__((address_space(3))) unsigned int*)l, 16, 0, 0);
}

// ---------------------------------------------------------------------------
// Kernel cvt: elementwise f32 -> bf16. n8 = #elements/8.
// ---------------------------------------------------------------------------
__global__ __launch_bounds__(256) void k_cvt(const float* __restrict__ src,
                                             unsigned short* __restrict__ dst, int n8)
{
    const int i = blockIdx.x * 256 + threadIdx.x;
    if (i < n8) {
        const f4* s = (const f4*)src + (size_t)i * 2;
        const f4 a = s[0], b = s[1];
        u4 o;
        o[0] = pack2(a[0], a[1]); o[1] = pack2(a[2], a[3]);
        o[2] = pack2(b[0], b[1]); o[3] = pack2(b[2], b[3]);
        *((u4*)dst + i) = o;
    }
}

// ---------------------------------------------------------------------------
// Kernel z2: z = tanh(xb @ Wbf^T + b), all-bf16 inputs, global_load_lds staging.
// Tile 64x128, BK=32, 4 waves (2x2 over 64x128 -> wave 32x64, acc 2x4).
// K-major LDS: A [4][64][8], B [4][128][8].
// ---------------------------------------------------------------------------
__global__ __launch_bounds__(256) void k_z2(const unsigned short* __restrict__ xb,
                                            const unsigned short* __restrict__ Wbf,
                                            const float* __restrict__ Wb,
                                            unsigned short* __restrict__ z)
{
    __shared__ unsigned short lds_a[4 * 64 * 8];    // 4 KB
    __shared__ unsigned short lds_b[4 * 128 * 8];   // 8 KB

    const int tid  = threadIdx.x;
    const int lane = tid & 63;
    const int w    = tid >> 6;
    const int wm   = w >> 1, wn = w & 1;
    const int q    = lane >> 4, r = lane & 15;
    const int m0   = blockIdx.x * 64;
    const int n0   = blockIdx.y * 128;

    f4 acc[2][4];
#pragma unroll
    for (int i = 0; i < 2; i++)
#pragma unroll
        for (int j = 0; j < 4; j++) { f4 zz = {0.f,0.f,0.f,0.f}; acc[i][j] = zz; }

    // staging pointers: wave w owns kseg q=w
    const unsigned short* ap0 = xb  + (size_t)(m0 + lane) * DIN + w * 8;
    const unsigned short* bp0 = Wbf + (size_t)(n0 + lane) * DIN + w * 8;
    const unsigned short* bp1 = Wbf + (size_t)(n0 + 64 + lane) * DIN + w * 8;
    unsigned short* la0 = &lds_a[w * 512 + lane * 8];
    unsigned short* lb0 = &lds_b[w * 1024 + lane * 8];
    unsigned short* lb1 = &lds_b[w * 1024 + 512 + lane * 8];

    for (int kk = 0; kk < DIN; kk += 32) {
        gload16(ap0 + kk, la0);
        gload16(bp0 + kk, lb0);
        gload16(bp1 + kk, lb1);
        __syncthreads();

        short8 af[2], bfr[4];
#pragma unroll
        for (int i = 0; i < 2; i++)
            af[i]  = *(const short8*)&lds_a[q * 512 + (wm * 32 + i * 16 + r) * 8];
#pragma unroll
        for (int j = 0; j < 4; j++)
            bfr[j] = *(const short8*)&lds_b[q * 1024 + (wn * 64 + j * 16 + r) * 8];
#pragma unroll
        for (int i = 0; i < 2; i++)
#pragma unroll
            for (int j = 0; j < 4; j++)
                acc[i][j] = __builtin_amdgcn_mfma_f32_16x16x32_bf16(af[i], bfr[j], acc[i][j], 0, 0, 0);
        __syncthreads();
    }

#pragma unroll
    for (int i = 0; i < 2; i++) {
#pragma unroll
        for (int j = 0; j < 4; j++) {
            const int col = n0 + wn * 64 + j * 16 + r;
            const float bias = Wb[col];
#pragma unroll
            for (int e = 0; e < 4; e++) {
                const int rowg = m0 + wm * 32 + i * 16 + q * 4 + e;
                z[(size_t)rowg * DA + col] = f2b(tanhf(acc[i][j][e] + bias));
            }
        }
    }
}

// ---------------------------------------------------------------------------
// Kernel uv2: dual GEMM sharing z staging, global_load_lds, K-major LDS,
// XCD-chunked swizzle (8960 = 8 * 1120 blocks).
//   scores[b,l,s] = U.z  -> f32 (alpha region of d_out)
//   T[b,l,s]      = V.z  -> bf16 (ws)
// 128x128 tile, BK=32, 4 waves 2x2, each wave 2x(4x4) acc.
// ---------------------------------------------------------------------------
__global__ __launch_bounds__(256) void k_uv2(const unsigned short* __restrict__ Ubf,
                                             const unsigned short* __restrict__ Vbf,
                                             const unsigned short* __restrict__ z,
                                             float* __restrict__ scores,
                                             unsigned short* __restrict__ T)
{
    // K-major LDS tiles: [4 ksegs][128 rows][8 elems], 8 KB each
    __shared__ unsigned short lds_u[4096];
    __shared__ unsigned short lds_v[4096];
    __shared__ unsigned short lds_z[4096];

    const int tid  = threadIdx.x;
    const int lane = tid & 63;
    const int w    = tid >> 6;
    const int wm   = w >> 1, wn = w & 1;
    const int q    = lane >> 4, r = lane & 15;

    // XCD-chunked bijective swizzle: XCD k gets contiguous work-chunk of 1120.
    const int f    = blockIdx.x;
    const int work = (f & 7) * 1120 + (f >> 3);
    const int mi   = work % 70;
    const int t    = work / 70;          // 0..127
    const int b    = t >> 5;
    const int nb   = t & 31;
    const int m0   = mi * 128;
    const int n0   = nb * 128;

    f4 accU[4][4], accV[4][4];
#pragma unroll
    for (int i = 0; i < 4; i++)
#pragma unroll
        for (int j = 0; j < 4; j++) {
            f4 zz = {0.f,0.f,0.f,0.f};
            accU[i][j] = zz; accV[i][j] = zz;
        }

    // staging: wave w owns kseg q=w, rows lane and 64+lane of each tile.
    // Edge rows clamped to last valid row (outputs for them are never written).
    const int mg0 = m0 + lane,      mg1 = m0 + 64 + lane;
    const int mr0 = mg0 < L_ ? mg0 : L_ - 1;
    const int mr1 = mg1 < L_ ? mg1 : L_ - 1;
    const int sg0 = n0 + lane,      sg1 = n0 + 64 + lane;
    const int sr0 = sg0 < S_ ? sg0 : S_ - 1;
    const int sr1 = sg1 < S_ ? sg1 : S_ - 1;

    const unsigned short* up0 = Ubf + (size_t)mr0 * DA + w * 8;
    const unsigned short* up1 = Ubf + (size_t)mr1 * DA + w * 8;
    const unsigned short* vp0 = Vbf + (size_t)mr0 * DA + w * 8;
    const unsigned short* vp1 = Vbf + (size_t)mr1 * DA + w * 8;
    const unsigned short* zp0 = z + ((size_t)b * S_ + sr0) * DA + w * 8;
    const unsigned short* zp1 = z + ((size_t)b * S_ + sr1) * DA + w * 8;

    unsigned short* lu0 = &lds_u[w * 1024 + lane * 8];
    unsigned short* lu1 = &lds_u[w * 1024 + 512 + lane * 8];
    unsigned short* lv0 = &lds_v[w * 1024 + lane * 8];
    unsigned short* lv1 = &lds_v[w * 1024 + 512 + lane * 8];
    unsigned short* lz0 = &lds_z[w * 1024 + lane * 8];
    unsigned short* lz1 = &lds_z[w * 1024 + 512 + lane * 8];

    for (int kk = 0; kk < DA; kk += 32) {
        gload16(up0 + kk, lu0); gload16(up1 + kk, lu1);
        gload16(vp0 + kk, lv0); gload16(vp1 + kk, lv1);
        gload16(zp0 + kk, lz0); gload16(zp1 + kk, lz1);
        __syncthreads();   // drains vmcnt -> tiles ready

        short8 fu[4], fv[4], fz[4];
#pragma unroll
        for (int i = 0; i < 4; i++) {
            fu[i] = *(const short8*)&lds_u[q * 1024 + (wm * 64 + i * 16 + r) * 8];
            fv[i] = *(const short8*)&lds_v[q * 1024 + (wm * 64 + i * 16 + r) * 8];
            fz[i] = *(const short8*)&lds_z[q * 1024 + (wn * 64 + i * 16 + r) * 8];
        }
#pragma unroll
        for (int i = 0; i < 4; i++)
#pragma unroll
            for (int j = 0; j < 4; j++) {
                accU[i][j] = __builtin_amdgcn_mfma_f32_16x16x32_bf16(fu[i], fz[j], accU[i][j], 0, 0, 0);
                accV[i][j] = __builtin_amdgcn_mfma_f32_16x16x32_bf16(fv[i], fz[j], accV[i][j], 0, 0, 0);
            }
        __syncthreads();
    }

#pragma unroll
    for (int i = 0; i < 4; i++) {
#pragma unroll
        for (int j = 0; j < 4; j++) {
            const int colg = n0 + wn * 64 + j * 16 + r;
#pragma unroll
            for (int e = 0; e < 4; e++) {
                const int rowg = m0 + wm * 64 + i * 16 + q * 4 + e;
                if (rowg < L_ && colg < S_) {
                    const size_t idx = ((size_t)b * L_ + rowg) * S_ + colg;
                    scores[idx] = accU[i][j][e];
                    T[idx]      = f2b(accV[i][j][e]);
                }
            }
        }
    }
}

// ---------------------------------------------------------------------------
// Kernel fsy2: per (b,l) row — softmax(scores) -> alpha (in-place),
// fused y = sum_s alpha*T + Vb. T is bf16; its load is issued in phase 0.
// ---------------------------------------------------------------------------
__global__ __launch_bounds__(256) void k_fsy2(float* __restrict__ sc,
                                              const unsigned short* __restrict__ T,
                                              const float* __restrict__ Vbias,
                                              float* __restrict__ y)
{
    const size_t rb = (size_t)blockIdx.x * S_;
    float* p = sc + rb;
    const unsigned short* tp = T + rb;
    const int tid = threadIdx.x;

    f4 v[4];
    us4 tv[4];
    float mx = -3.4e38f;
#pragma unroll
    for (int j = 0; j < 4; j++) {
        const int vi = tid + j * 256;
        if (vi < S_ / 4) {
            v[j]  = ((const f4*)p)[vi];
            tv[j] = ((const us4*)tp)[vi];
            mx = fmaxf(mx, fmaxf(fmaxf(v[j][0], v[j][1]), fmaxf(v[j][2], v[j][3])));
        }
    }
#pragma unroll
    for (int off = 32; off > 0; off >>= 1) mx = fmaxf(mx, __shfl_xor(mx, off, 64));

    __shared__ float red[12];
    if ((tid & 63) == 0) red[tid >> 6] = mx;
    __syncthreads();
    mx = fmaxf(fmaxf(red[0], red[1]), fmaxf(red[2], red[3]));

    float s = 0.f;
#pragma unroll
    for (int j = 0; j < 4; j++) {
        const int vi = tid + j * 256;
        if (vi < S_ / 4) {
#pragma unroll
            for (int c = 0; c < 4; c++) { v[j][c] = __expf(v[j][c] - mx); s += v[j][c]; }
        }
    }
#pragma unroll
    for (int off = 32; off > 0; off >>= 1) s += __shfl_xor(s, off, 64);
    if ((tid & 63) == 0) red[4 + (tid >> 6)] = s;
    __syncthreads();
    s = red[4] + red[5] + red[6] + red[7];
    const float inv = 1.f / s;

    float yp = 0.f;
#pragma unroll
    for (int j = 0; j < 4; j++) {
        const int vi = tid + j * 256;
        if (vi < S_ / 4) {
            f4 o = v[j];
            o[0] *= inv; o[1] *= inv; o[2] *= inv; o[3] *= inv;
            ((f4*)p)[vi] = o;
            yp += o[0] * b2f(tv[j][0]) + o[1] * b2f(tv[j][1])
                + o[2] * b2f(tv[j][2]) + o[3] * b2f(tv[j][3]);
        }
    }
#pragma unroll
    for (int off = 32; off > 0; off >>= 1) yp += __shfl_xor(yp, off, 64);
    if ((tid & 63) == 0) red[8 + (tid >> 6)] = yp;
    __syncthreads();
    if (tid == 0) {
        const int l = (int)(blockIdx.x % (unsigned)L_);
        y[blockIdx.x] = red[8] + red[9] + red[10] + red[11] + Vbias[l];
    }
}

// ===========================================================================
// ===== Fallback path (verified round-0 kernels), used if ws too small  =====
// ===========================================================================
__global__ __launch_bounds__(256) void k_z(const float* __restrict__ x,
                                           const float* __restrict__ Ww,
                                           const float* __restrict__ Wb,
                                           unsigned short* __restrict__ z)
{
    __shared__ unsigned short lds_a[128 * 32];
    __shared__ unsigned short lds_b[128 * 32];

    const int tid  = threadIdx.x;
    const int lane = tid & 63;
    const int w    = tid >> 6;
    const int wm   = w >> 1, wn = w & 1;
    const int q    = lane >> 4, r = lane & 15;
    const int m0   = blockIdx.x * 128;
    const int n0   = blockIdx.y * 128;

    f4 acc[4][4];
#pragma unroll
    for (int i = 0; i < 4; i++)
#pragma unroll
        for (int j = 0; j < 4; j++) { f4 zz = {0.f,0.f,0.f,0.f}; acc[i][j] = zz; }

    const int row  = tid >> 1;
    const int half = tid & 1;

    for (int kk = 0; kk < DIN; kk += 32) {
        {
            const f4* src = (const f4*)(x + (size_t)(m0 + row) * DIN + kk + half * 16);
            f4 v0 = src[0], v1 = src[1], v2 = src[2], v3 = src[3];
            u4* dst = (u4*)&lds_a[row * 32 + half * 16];
            u4 o0, o1;
            o0[0] = pack2(v0[0], v0[1]); o0[1] = pack2(v0[2], v0[3]);
            o0[2] = pack2(v1[0], v1[1]); o0[3] = pack2(v1[2], v1[3]);
            o1[0] = pack2(v2[0], v2[1]); o1[1] = pack2(v2[2], v2[3]);
            o1[2] = pack2(v3[0], v3[1]); o1[3] = pack2(v3[2], v3[3]);
            dst[0] = o0; dst[1] = o1;
        }
        {
            const f4* src = (const f4*)(Ww + (size_t)(n0 + row) * DIN + kk + half * 16);
            f4 v0 = src[0], v1 = src[1], v2 = src[2], v3 = src[3];
            u4* dst = (u4*)&lds_b[row * 32 + half * 16];
            u4 o0, o1;
            o0[0] = pack2(v0[0], v0[1]); o0[1] = pack2(v0[2], v0[3]);
            o0[2] = pack2(v1[0], v1[1]); o0[3] = pack2(v1[2], v1[3]);
            o1[0] = pack2(v2[0], v2[1]); o1[1] = pack2(v2[2], v2[3]);
            o1[2] = pack2(v3[0], v3[1]); o1[3] = pack2(v3[2], v3[3]);
            dst[0] = o0; dst[1] = o1;
        }
        __syncthreads();

        short8 af[4], bfr[4];
#pragma unroll
        for (int i = 0; i < 4; i++) {
            af[i]  = *(const short8*)&lds_a[(wm * 64 + i * 16 + r) * 32 + q * 8];
            bfr[i] = *(const short8*)&lds_b[(wn * 64 + i * 16 + r) * 32 + q * 8];
        }
#pragma unroll
        for (int i = 0; i < 4; i++)
#pragma unroll
            for (int j = 0; j < 4; j++)
                acc[i][j] = __builtin_amdgcn_mfma_f32_16x16x32_bf16(af[i], bfr[j], acc[i][j], 0, 0, 0);
        __syncthreads();
    }

#pragma unroll
    for (int i = 0; i < 4; i++) {
#pragma unroll
        for (int j = 0; j < 4; j++) {
            const int col = n0 + wn * 64 + j * 16 + r;
            const float bias = Wb[col];
#pragma unroll
            for (int e = 0; e < 4; e++) {
                const int rowg = m0 + wm * 64 + i * 16 + q * 4 + e;
                z[(size_t)rowg * DA + col] = f2b(tanhf(acc[i][j][e] + bias));
            }
        }
    }
}

__global__ __launch_bounds__(256) void k_scores(const float* __restrict__ U,
                                                const unsigned short* __restrict__ z,
                                                float* __restrict__ out)
{
    __shared__ unsigned short lds_a[128 * 32];
    __shared__ unsigned short lds_b[128 * 32];

    const int tid  = threadIdx.x;
    const int lane = tid & 63;
    const int w    = tid >> 6;
    const int wm   = w >> 1, wn = w & 1;
    const int q    = lane >> 4, r = lane & 15;
    const int b    = blockIdx.z;
    const int m0   = blockIdx.x * 128;
    const int n0   = blockIdx.y * 128;

    f4 acc[4][4];
#pragma unroll
    for (int i = 0; i < 4; i++)
#pragma unroll
        for (int j = 0; j < 4; j++) { f4 zz = {0.f,0.f,0.f,0.f}; acc[i][j] = zz; }

    const int row  = tid >> 1;
    const int half = tid & 1;
    const int brow = tid >> 2;
    const int bseg = tid & 3;

    for (int kk = 0; kk < DA; kk += 32) {
        {
            u4* dst = (u4*)&lds_a[row * 32 + half * 16];
            const int gm = m0 + row;
            if (gm < L_) {
                const f4* src = (const f4*)(U + (size_t)gm * DA + kk + half * 16);
                f4 v0 = src[0], v1 = src[1], v2 = src[2], v3 = src[3];
                u4 o0, o1;
                o0[0] = pack2(v0[0], v0[1]); o0[1] = pack2(v0[2], v0[3]);
                o0[2] = pack2(v1[0], v1[1]); o0[3] = pack2(v1[2], v1[3]);
                o1[0] = pack2(v2[0], v2[1]); o1[1] = pack2(v2[2], v2[3]);
                o1[2] = pack2(v3[0], v3[1]); o1[3] = pack2(v3[2], v3[3]);
                dst[0] = o0; dst[1] = o1;
            } else {
                u4 zz = {0,0,0,0}; dst[0] = zz; dst[1] = zz;
            }
        }
#pragma unroll
        for (int jj = 0; jj < 2; jj++) {
            const int rr = brow + jj * 64;
            const int gs = n0 + rr;
            u4* dst = (u4*)&lds_b[rr * 32 + bseg * 8];
            if (gs < S_) {
                *dst = *(const u4*)&z[((size_t)(b * S_ + gs)) * DA + kk + bseg * 8];
            } else {
                u4 zz = {0,0,0,0}; *dst = zz;
            }
        }
        __syncthreads();

        short8 af[4], bfr[4];
#pragma unroll
        for (int i = 0; i < 4; i++) {
            af[i]  = *(const short8*)&lds_a[(wm * 64 + i * 16 + r) * 32 + q * 8];
            bfr[i] = *(const short8*)&lds_b[(wn * 64 + i * 16 + r) * 32 + q * 8];
        }
#pragma unroll
        for (int i = 0; i < 4; i++)
#pragma unroll
            for (int j = 0; j < 4; j++)
                acc[i][j] = __builtin_amdgcn_mfma_f32_16x16x32_bf16(af[i], bfr[j], acc[i][j], 0, 0, 0);
        __syncthreads();
    }

#pragma unroll
    for (int i = 0; i < 4; i++) {
#pragma unroll
        for (int j = 0; j < 4; j++) {
            const int colg = n0 + wn * 64 + j * 16 + r;
#pragma unroll
            for (int e = 0; e < 4; e++) {
                const int rowg = m0 + wm * 64 + i * 16 + q * 4 + e;
                if (rowg < L_ && colg < S_)
                    out[((size_t)b * L_ + rowg) * S_ + colg] = acc[i][j][e];
            }
        }
    }
}

__global__ __launch_bounds__(256) void k_softmax(float* __restrict__ a)
{
    float* p = a + (size_t)blockIdx.x * S_;
    const int tid = threadIdx.x;

    f4 v[4];
    float mx = -3.4e38f;
#pragma unroll
    for (int j = 0; j < 4; j++) {
        const int vi = tid + j * 256;
        if (vi < S_ / 4) {
            v[j] = ((const f4*)p)[vi];
            mx = fmaxf(mx, fmaxf(fmaxf(v[j][0], v[j][1]), fmaxf(v[j][2], v[j][3])));
        }
    }
#pragma unroll
    for (int off = 32; off > 0; off >>= 1) mx = fmaxf(mx, __shfl_xor(mx, off, 64));

    __shared__ float red[8];
    if ((tid & 63) == 0) red[tid >> 6] = mx;
    __syncthreads();
    mx = fmaxf(fmaxf(red[0], red[1]), fmaxf(red[2], red[3]));

    float s = 0.f;
#pragma unroll
    for (int j = 0; j < 4; j++) {
        const int vi = tid + j * 256;
        if (vi < S_ / 4) {
#pragma unroll
            for (int c = 0; c < 4; c++) { v[j][c] = __expf(v[j][c] - mx); s += v[j][c]; }
        }
    }
#pragma unroll
    for (int off = 32; off > 0; off >>= 1) s += __shfl_xor(s, off, 64);
    if ((tid & 63) == 0) red[4 + (tid >> 6)] = s;
    __syncthreads();
    s = red[4] + red[5] + red[6] + red[7];

    const float inv = 1.f / s;
#pragma unroll
    for (int j = 0; j < 4; j++) {
        const int vi = tid + j * 256;
        if (vi < S_ / 4) {
            f4 o = v[j]; o[0] *= inv; o[1] *= inv; o[2] *= inv; o[3] *= inv;
            ((f4*)p)[vi] = o;
        }
    }
}

__global__ __launch_bounds__(256) void k_transpose(const unsigned short* __restrict__ z,
                                                   unsigned short* __restrict__ zT)
{
    __shared__ unsigned short t[32][33];
    const int b  = blockIdx.z;
    const int s0 = blockIdx.x * 32;
    const int a0 = blockIdx.y * 32;
    const int c  = threadIdx.x & 31;
    const int r4 = threadIdx.x >> 5;

#pragma unroll
    for (int i = 0; i < 4; i++) {
        const int sl = r4 * 4 + i;
        t[sl][c] = z[((size_t)(b * S_ + s0 + sl)) * DA + a0 + c];
    }
    __syncthreads();
#pragma unroll
    for (int i = 0; i < 4; i++) {
        const int al = r4 * 4 + i;
        zT[((size_t)(b * DA + a0 + al)) * S_ + s0 + c] = t[c][al];
    }
}

__global__ __launch_bounds__(256) void k_mv(const float* __restrict__ alpha,
                                            const unsigned short* __restrict__ zT,
                                            const float* __restrict__ Vw,
                                            const float* __restrict__ Vb,
                                            float* __restrict__ y)
{
    __shared__ unsigned short lds_a[64 * 32];
    __shared__ unsigned short lds_b[512 * 32];
    __shared__ float yred[64];

    const int tid  = threadIdx.x;
    const int lane = tid & 63;
    const int w    = tid >> 6;
    const int q    = lane >> 4, r = lane & 15;
    const int b    = blockIdx.y;
    const int m0   = blockIdx.x * 64;

    if (tid < 64) yred[tid] = 0.f;

    f4 acc[4][8];
#pragma unroll
    for (int i = 0; i < 4; i++)
#pragma unroll
        for (int j = 0; j < 8; j++) { f4 zz = {0.f,0.f,0.f,0.f}; acc[i][j] = zz; }

    const int arow = tid >> 2;
    const int aseg = tid & 3;

    for (int kk = 0; kk < S_; kk += 32) {
        {
            u4* dst = (u4*)&lds_a[arow * 32 + aseg * 8];
            const int gl = m0 + arow;
            if (gl < L_) {
                const f4* src = (const f4*)(alpha + ((size_t)b * L_ + gl) * S_ + kk + aseg * 8);
                f4 v0 = src[0], v1 = src[1];
                u4 o;
                o[0] = pack2(v0[0], v0[1]); o[1] = pack2(v0[2], v0[3]);
                o[2] = pack2(v1[0], v1[1]); o[3] = pack2(v1[2], v1[3]);
                *dst = o;
            } else {
                u4 zz = {0,0,0,0}; *dst = zz;
            }
        }
#pragma unroll
        for (int jj = 0; jj < 8; jj++) {
            const int rr = arow + jj * 64;
            *(u4*)&lds_b[rr * 32 + aseg * 8] =
                *(const u4*)&zT[((size_t)(b * DA + rr)) * S_ + kk + aseg * 8];
        }
        __syncthreads();

        short8 af[4], bfr[8];
#pragma unroll
        for (int i = 0; i < 4; i++)
            af[i] = *(const short8*)&lds_a[(i * 16 + r) * 32 + q * 8];
#pragma unroll
        for (int j = 0; j < 8; j++)
            bfr[j] = *(const short8*)&lds_b[(w * 128 + j * 16 + r) * 32 + q * 8];
#pragma unroll
        for (int i = 0; i < 4; i++)
#pragma unroll
            for (int j = 0; j < 8; j++)
                acc[i][j] = __builtin_amdgcn_mfma_f32_16x16x32_bf16(af[i], bfr[j], acc[i][j], 0, 0, 0);
        __syncthreads();
    }

#pragma unroll
    for (int i = 0; i < 4; i++) {
#pragma unroll
        for (int e = 0; e < 4; e++) {
            const int rowl = i * 16 + q * 4 + e;
            const int gl = m0 + rowl;
            if (gl < L_) {
                float p = 0.f;
#pragma unroll
                for (int j = 0; j < 8; j++) {
                    const int col = w * 128 + j * 16 + r;
                    p += acc[i][j][e] * Vw[(size_t)gl * DA + col];
                }
                atomicAdd(&yred[rowl], p);
            }
        }
    }
    __syncthreads();
    if (tid < 64 && (m0 + tid) < L_)
        y[b * L_ + m0 + tid] = yred[tid] + Vb[m0 + tid];
}

// ---------------------------------------------------------------------------
extern "C" void kernel_launch(void* const* d_in, const int* in_sizes, int n_in,
                              void* d_out, int out_size, void* d_ws, size_t ws_size,
                              hipStream_t stream)
{
    const float* x  = (const float*)d_in[0];
    const float* Ww = (const float*)d_in[1];
    const float* Wb = (const float*)d_in[2];
    const float* Uw = (const float*)d_in[3];
    const float* Vw = (const float*)d_in[4];
    const float* Vb = (const float*)d_in[5];

    float* y     = (float*)d_out;
    float* alpha = y + (size_t)B_ * L_;   // outputs concatenated: y then alpha

    // Workspace layout: [z][xb][Wbf][Ubf][Vbf][T bf16]  (~354 MB total)
    const size_t z_bytes  = (size_t)B_ * S_ * DA * 2;     //  16,384,000
    const size_t xb_bytes = (size_t)B_ * S_ * DIN * 2;    //  32,768,000
    const size_t wb_bytes = (size_t)DA * DIN * 2;         //   1,048,576
    const size_t uv_bytes = (size_t)L_ * DA * 2;          //   9,135,104
    const size_t T_bytes  = (size_t)B_ * L_ * S_ * 2;     // 285,472,000
    const size_t need     = z_bytes + xb_bytes + wb_bytes + 2 * uv_bytes + T_bytes;

    unsigned short* z   = (unsigned short*)d_ws;
    unsigned short* xb  = (unsigned short*)((char*)d_ws + z_bytes);
    unsigned short* Wbf = (unsigned short*)((char*)d_ws + z_bytes + xb_bytes);
    unsigned short* Ubf = (unsigned short*)((char*)d_ws + z_bytes + xb_bytes + wb_bytes);
    unsigned short* Vbf = (unsigned short*)((char*)d_ws + z_bytes + xb_bytes + wb_bytes + uv_bytes);
    unsigned short* T   = (unsigned short*)((char*)d_ws + z_bytes + xb_bytes + wb_bytes + 2 * uv_bytes);

    if (ws_size >= need) {
        const int n8x = (B_ * S_ * DIN) / 8;
        const int n8w = (DA * DIN) / 8;
        const int n8u = (L_ * DA) / 8;
        k_cvt<<<dim3((n8x + 255) / 256), dim3(256), 0, stream>>>(x,  xb,  n8x);
        k_cvt<<<dim3((n8w + 255) / 256), dim3(256), 0, stream>>>(Ww, Wbf, n8w);
        k_cvt<<<dim3((n8u + 255) / 256), dim3(256), 0, stream>>>(Uw, Ubf, n8u);
        k_cvt<<<dim3((n8u + 255) / 256), dim3(256), 0, stream>>>(Vw, Vbf, n8u);
        k_z2<<<dim3(250, 4), dim3(256), 0, stream>>>(xb, Wbf, Wb, z);
        k_uv2<<<dim3(8960), dim3(256), 0, stream>>>(Ubf, Vbf, z, alpha, T);
        k_fsy2<<<dim3(B_ * L_), dim3(256), 0, stream>>>(alpha, T, Vb, y);
    } else {
        // Fallback: verified round-0 path (needs only ~33 MB of ws)
        unsigned short* zT = z + (size_t)B_ * S_ * DA;
        k_z<<<dim3(125, 4), dim3(256), 0, stream>>>(x, Ww, Wb, z);
        k_scores<<<dim3(70, 32, B_), dim3(256), 0, stream>>>(Uw, z, alpha);
        k_softmax<<<dim3(B_ * L_), dim3(256), 0, stream>>>(alpha);
        k_transpose<<<dim3(125, 16, B_), dim3(256), 0, stream>>>(z, zT);
        k_mv<<<dim3(140, B_), dim3(256), 0, stream>>>(alpha, zT, Vw, Vb, y);
    }
}